// Round 1
// baseline (321.328 us; speedup 1.0000x reference)
//
#include <hip/hip_runtime.h>
#include <hip/hip_bf16.h>
#include <math.h>

// CovidModel forward:
//   A[d][s] = A[d-1][s] * r[d]^(1/T_serial[s]),  A[-1..-J] = warmup_A
//   M[d][s] = rho[s] * sum_j pi[j][s] * A_ext[J+d-j-1][s]
// Closed form: A[d][s] = wA[s] * 2^(L[d]/T_serial[s]),  L[d] = prefix sum of log2 r.
// Kernel 1: length-T block scan of log2(r) (accumulated in double).
// Kernel 2: each thread owns one sample s and a chunk of days; sliding
//           10-register window of A values, 1 exp2f per day, 10 FMAs per output.

#define SCAN_THREADS 1024

__global__ void prefix_log2_kernel(const float* __restrict__ r,
                                   float* __restrict__ L,
                                   int T, int chunk) {
    __shared__ double ssum[SCAN_THREADS];
    const int t = threadIdx.x;
    const int begin = t * chunk;
    const int end = min(begin + chunk, T);

    double local = 0.0;
    for (int i = begin; i < end; ++i) local += (double)log2f(r[i]);
    ssum[t] = local;
    __syncthreads();

    // Hillis-Steele inclusive scan over per-thread sums (10 steps).
    for (int off = 1; off < SCAN_THREADS; off <<= 1) {
        double v = (t >= off) ? ssum[t - off] : 0.0;
        __syncthreads();
        ssum[t] += v;
        __syncthreads();
    }

    double run = (t == 0) ? 0.0 : ssum[t - 1];   // exclusive prefix
    for (int i = begin; i < end; ++i) {
        run += (double)log2f(r[i]);
        L[i] = (float)run;                        // inclusive prefix, fp32 out
    }
}

template <int J>
__global__ void forecast_kernel(const float* __restrict__ L,
                                const float* __restrict__ warmup_A,
                                const float* __restrict__ T_serial,
                                const float* __restrict__ rho_M,
                                const float* __restrict__ pi_M,
                                float* __restrict__ out,
                                int T, int S, int dchunk) {
    const int s = blockIdx.x * blockDim.x + threadIdx.x;
    if (s >= S) return;

    const int d0   = blockIdx.y * dchunk;
    const int dend = min(d0 + dchunk, T);

    const float invT = 1.0f / T_serial[s];
    const float rho  = rho_M[s];
    const float wA   = warmup_A[(J - 1) * S + s];

    float pi[J];
#pragma unroll
    for (int j = 0; j < J; ++j) pi[j] = pi_M[j * S + s];

    // Window a[j] = A_ext value at day (d-1-j); init for d = d0.
    float a[J];
#pragma unroll
    for (int j = 0; j < J; ++j) {
        const int t = d0 - 1 - j;
        a[j] = (t >= 0) ? wA * exp2f(L[t] * invT)
                        : warmup_A[(J + t) * S + s];
    }

    for (int d = d0; d < dend; ++d) {
        float m = 0.0f;
#pragma unroll
        for (int j = 0; j < J; ++j) m = fmaf(pi[j], a[j], m);
        out[(size_t)d * S + s] = rho * m;

        const float newA = wA * exp2f(L[d] * invT);
#pragma unroll
        for (int j = J - 1; j >= 1; --j) a[j] = a[j - 1];
        a[0] = newA;
    }
}

extern "C" void kernel_launch(void* const* d_in, const int* in_sizes, int n_in,
                              void* d_out, int out_size, void* d_ws, size_t ws_size,
                              hipStream_t stream) {
    const float* r_t      = (const float*)d_in[0];   // (1, T)
    const float* warmup_A = (const float*)d_in[1];   // (J, S)
    const float* T_serial = (const float*)d_in[2];   // (S,)
    const float* rho_M    = (const float*)d_in[3];   // (S,)
    const float* pi_M     = (const float*)d_in[4];   // (J, S)
    float* out            = (float*)d_out;           // (T, S)

    const int T = in_sizes[0];
    const int S = in_sizes[2];
    // J fixed at 10 (template parameter); in_sizes[1] == J*S.

    float* L = (float*)d_ws;                          // T floats of scratch

    const int chunk = (T + SCAN_THREADS - 1) / SCAN_THREADS;
    prefix_log2_kernel<<<1, SCAN_THREADS, 0, stream>>>(r_t, L, T, chunk);

    const int dchunk = 128;
    dim3 block(256, 1, 1);
    dim3 grid((S + 255) / 256, (T + dchunk - 1) / dchunk, 1);
    forecast_kernel<10><<<grid, block, 0, stream>>>(L, warmup_A, T_serial, rho_M,
                                                    pi_M, out, T, S, dchunk);
}